// Round 12
// baseline (1204.370 us; speedup 1.0000x reference)
//
#include <hip/hip_runtime.h>
#include <hip/hip_bf16.h>
#include <stdint.h>

typedef __bf16 bf16;
typedef __attribute__((ext_vector_type(4))) __bf16 bf16x4;
typedef __attribute__((ext_vector_type(8))) __bf16 bf16x8;
typedef __attribute__((ext_vector_type(4))) float f32x4;

#define DEVI __device__ __forceinline__

// ---------------- constants ----------------
constexpr int BATCH = 2, SEQ = 2048, HID = 1024, NHEAD = 16, HDIM = 64;
constexpr int H3 = 3072;                 // 3*HID
constexpr int MROWS = BATCH * SEQ;       // 4096
constexpr int KEXP = 9;                  // 1 (silu) + 8 spline coefs
constexpr int K1DIM = H3 * KEXP;         // 27648
constexpr int K2DIM = HID * KEXP;        // 9216

// workspace layout (bytes)
constexpr size_t WQ_OFF  = 0;
constexpr size_t AQ_OFF  = 169869312;
constexpr size_t CQ_OFF  = AQ_OFF + 226492416;
constexpr size_t QR_OFF  = CQ_OFF + 50331648;
constexpr size_t KR_OFF  = QR_OFF + 8388608;
constexpr size_t VB_OFF  = KR_OFF + 8388608;
constexpr size_t CTX_OFF = VB_OFF + 8388608;
constexpr size_t A2_OFF  = 0;                       // reuse Wq region (dead after gemm1)
constexpr size_t W2_OFF  = 75497472;
constexpr size_t MB_OFF  = W2_OFF + 18874368;       // bf16 mask (8.4MB), dead-Wq region

DEVI void gld_lds16(const void* g, void* l) {
  __builtin_amdgcn_global_load_lds((const __attribute__((address_space(1))) void*)g,
                                   (__attribute__((address_space(3))) void*)l, 16, 0, 0);
}

#define WAITVM0() asm volatile("s_waitcnt vmcnt(0)" ::: "memory")
#define MEMFENCE() asm volatile("" ::: "memory")
#define BARRIER() do { __builtin_amdgcn_s_barrier(); asm volatile("" ::: "memory"); } while (0)

// silu + cubic B-spline bases on uniform grid h=0.4, knots g[j]=(j-3)*0.4-1, j=0..11
DEVI void silu_bases(float x, float* o9) {
  o9[0] = x / (1.0f + __expf(-x));
  float g[12];
#pragma unroll
  for (int j = 0; j < 12; ++j) g[j] = (float)(j - 3) * 0.4f - 1.0f;
  float b[11];
#pragma unroll
  for (int j = 0; j < 11; ++j) b[j] = (x >= g[j] && x < g[j + 1]) ? 1.0f : 0.0f;
#pragma unroll
  for (int k = 1; k <= 3; ++k) {
    const float inv = (k == 1) ? 2.5f : (k == 2) ? 1.25f : (1.0f / 1.2f);
#pragma unroll
    for (int j = 0; j + k < 11; ++j) {
      b[j] = (x - g[j]) * inv * b[j] + (g[j + k + 1] - x) * inv * b[j + 1];
    }
  }
#pragma unroll
  for (int c = 0; c < 8; ++c) o9[1 + c] = b[c];
}

// ---------------- weight repack (LDS-coalesced) ----------------
__global__ __launch_bounds__(256)
void wprep_kernel(const float* __restrict__ bw, const float* __restrict__ sw,
                  const float* __restrict__ sc, bf16* __restrict__ W, int KK) {
  __shared__ bf16 buf[256 * KEXP];
  const int tid = threadIdx.x;
  const int n = blockIdx.y;
  const int i0 = blockIdx.x * 256;
  const size_t idx = (size_t)n * KK + i0 + tid;
  float base = bw[idx];
  float scal = sc[idx];
  const float4* sp = (const float4*)(sw + idx * 8);
  float4 s0 = sp[0], s1 = sp[1];
  bf16* o = buf + tid * KEXP;
  o[0] = (bf16)base;
  o[1] = (bf16)(s0.x * scal); o[2] = (bf16)(s0.y * scal);
  o[3] = (bf16)(s0.z * scal); o[4] = (bf16)(s0.w * scal);
  o[5] = (bf16)(s1.x * scal); o[6] = (bf16)(s1.y * scal);
  o[7] = (bf16)(s1.z * scal); o[8] = (bf16)(s1.w * scal);
  __syncthreads();
  bf16* dst = W + (size_t)n * KK * KEXP + (size_t)i0 * KEXP;
#pragma unroll
  for (int j = tid; j < 256 * KEXP / 8; j += 256)
    *(bf16x8*)(dst + j * 8) = *(const bf16x8*)(buf + j * 8);
}

// ---------------- activation expansion, LDS-coalesced ----------------
__global__ __launch_bounds__(256)
void act_qkv_kernel(const float* __restrict__ qin, const float* __restrict__ kin,
                    const float* __restrict__ vin, bf16* __restrict__ A) {
  __shared__ bf16 buf[256 * KEXP];
  const int tid = threadIdx.x;
  const int m = blockIdx.y;
  const int i0 = blockIdx.x * 256;
  const int i = i0 + tid;
  const int which = i >> 10, off = i & 1023;
  const float* src = (which == 0) ? qin : (which == 1) ? kin : vin;
  float x = src[(size_t)m * HID + off];
  float o9[9];
  silu_bases(x, o9);
  bf16* o = buf + tid * KEXP;
#pragma unroll
  for (int c = 0; c < 9; ++c) o[c] = (bf16)o9[c];
  __syncthreads();
  bf16* dst = A + (size_t)m * K1DIM + (size_t)i0 * KEXP;
#pragma unroll
  for (int j = tid; j < 256 * KEXP / 8; j += 256)
    *(bf16x8*)(dst + j * 8) = *(const bf16x8*)(buf + j * 8);
}

__global__ __launch_bounds__(256)
void act_out_kernel(const float* __restrict__ ctx, bf16* __restrict__ A) {
  __shared__ bf16 buf[256 * KEXP];
  const int tid = threadIdx.x;
  const int m = blockIdx.y;
  const int i0 = blockIdx.x * 256;
  float x = ctx[(size_t)m * HID + i0 + tid];
  float o9[9];
  silu_bases(x, o9);
  bf16* o = buf + tid * KEXP;
#pragma unroll
  for (int c = 0; c < 9; ++c) o[c] = (bf16)o9[c];
  __syncthreads();
  bf16* dst = A + (size_t)m * K2DIM + (size_t)i0 * KEXP;
#pragma unroll
  for (int j = tid; j < 256 * KEXP / 8; j += 256)
    *(bf16x8*)(dst + j * 8) = *(const bf16x8*)(buf + j * 8);
}

// ---------------- mask fp32 -> bf16 ----------------
__global__ __launch_bounds__(256)
void maskprep_kernel(const float* __restrict__ m, bf16* __restrict__ mb) {
  int i = (blockIdx.x * 256 + threadIdx.x) * 4;
  float4 v = *(const float4*)(m + i);
  bf16x4 o = { (bf16)v.x, (bf16)v.y, (bf16)v.z, (bf16)v.w };
  *(bf16x4*)(mb + i) = o;
}

// ---------------- gemm1: 128x128 tile (ROUND-4 EXACT CONFIG, measured best) ----------
// 690us / MfmaUtil 45% / conflicts 0. Confirmed optimum for this structure:
// wider tiles (r11: 128x192, 2/CU -> 724us), dbuf 64KiB (r6: 1120us), BK=32
// pipeline (r8: 850us), XCD swizzle (r5: +20us) ALL regress. 3 resident
// blocks/CU is the binding constraint; do not reduce.
__global__ __launch_bounds__(256, 2)
void gemm_kernel(const bf16* __restrict__ A, const bf16* __restrict__ Bw,
                 float* __restrict__ C, int N, int K) {
  __shared__ bf16 As[128 * 64];
  __shared__ bf16 Bs[128 * 64];
  const int tid = threadIdx.x;
  const int lane = tid & 63;
  const int l15 = lane & 15, lq = lane >> 4;
  const int wid = tid >> 6;
  const int wm = (wid >> 1) * 64, wn = (wid & 1) * 64;
  const int bm = blockIdx.y, bn = blockIdx.x;
  f32x4 acc[4][4] = {};
  const int srow = tid >> 3;
  const int schk = (tid & 7) ^ (srow & 7);
  const bf16* aB = A + (size_t)(bm * 128 + srow) * K + schk * 8;
  const bf16* bB = Bw + (size_t)(bn * 128 + srow) * K + schk * 8;

  int aoff[2][4], boff[2][4];
#pragma unroll
  for (int ks = 0; ks < 2; ++ks) {
#pragma unroll
    for (int f = 0; f < 4; ++f) {
      int arow = wm + f * 16 + l15;
      int brow = wn + f * 16 + l15;
      aoff[ks][f] = arow * 64 + (((ks * 4 + lq) ^ (arow & 7)) * 8);
      boff[ks][f] = brow * 64 + (((ks * 4 + lq) ^ (brow & 7)) * 8);
    }
  }

  for (int kt = 0; kt < K; kt += 64) {
#pragma unroll
    for (int r = 0; r < 4; ++r) {
      gld_lds16(aB + (size_t)(r * 32) * K + kt, As + r * 2048 + tid * 8);
      gld_lds16(bB + (size_t)(r * 32) * K + kt, Bs + r * 2048 + tid * 8);
    }
    __syncthreads();
#pragma unroll
    for (int ks = 0; ks < 2; ++ks) {
      bf16x8 af[4], bfr[4];
#pragma unroll
      for (int mf = 0; mf < 4; ++mf)
        af[mf] = *(const bf16x8*)&As[aoff[ks][mf]];
#pragma unroll
      for (int nf = 0; nf < 4; ++nf)
        bfr[nf] = *(const bf16x8*)&Bs[boff[ks][nf]];
#pragma unroll
      for (int mf = 0; mf < 4; ++mf)
#pragma unroll
        for (int nf = 0; nf < 4; ++nf)
          acc[mf][nf] = __builtin_amdgcn_mfma_f32_16x16x32_bf16(af[mf], bfr[nf], acc[mf][nf], 0, 0, 0);
    }
    __syncthreads();
  }
#pragma unroll
  for (int mf = 0; mf < 4; ++mf)
#pragma unroll
    for (int nf = 0; nf < 4; ++nf)
#pragma unroll
      for (int r = 0; r < 4; ++r) {
        int row = bm * 128 + wm + mf * 16 + lq * 4 + r;
        int col = bn * 128 + wn + nf * 16 + l15;
        C[(size_t)row * N + col] = acc[mf][nf][r];
      }
}

// ---------------- gemm2: 64x128 tile (verified round 10) ----------------
__global__ __launch_bounds__(256, 2)
void gemm2_kernel(const bf16* __restrict__ A, const bf16* __restrict__ Bw,
                  float* __restrict__ C, int N, int K) {
  __shared__ bf16 As[64 * 64];       // 8 KiB
  __shared__ bf16 Bs[128 * 64];      // 16 KiB
  const int tid = threadIdx.x;
  const int lane = tid & 63;
  const int l15 = lane & 15, lq = lane >> 4;
  const int wid = tid >> 6;
  const int wr = wid >> 1, wc = wid & 1;   // wave tile 32(M) x 64(N)
  const int bm = blockIdx.y, bn = blockIdx.x;
  f32x4 acc[2][4] = {};
  const int srow = tid >> 3;
  const int schk = (tid & 7) ^ (srow & 7);
  const bf16* aB = A + (size_t)(bm * 64 + srow) * K + schk * 8;
  const bf16* bB = Bw + (size_t)(bn * 128 + srow) * K + schk * 8;

  int aoff[2][2], boff[2][4];
#pragma unroll
  for (int ks = 0; ks < 2; ++ks) {
#pragma unroll
    for (int f = 0; f < 2; ++f) {
      int arow = wr * 32 + f * 16 + l15;
      aoff[ks][f] = arow * 64 + (((ks * 4 + lq) ^ (arow & 7)) * 8);
    }
#pragma unroll
    for (int f = 0; f < 4; ++f) {
      int brow = wc * 64 + f * 16 + l15;
      boff[ks][f] = brow * 64 + (((ks * 4 + lq) ^ (brow & 7)) * 8);
    }
  }

  for (int kt = 0; kt < K; kt += 64) {
#pragma unroll
    for (int r = 0; r < 2; ++r)
      gld_lds16(aB + (size_t)(r * 32) * K + kt, As + r * 2048 + tid * 8);
#pragma unroll
    for (int r = 0; r < 4; ++r)
      gld_lds16(bB + (size_t)(r * 32) * K + kt, Bs + r * 2048 + tid * 8);
    __syncthreads();
#pragma unroll
    for (int ks = 0; ks < 2; ++ks) {
      bf16x8 af[2], bfr[4];
#pragma unroll
      for (int mf = 0; mf < 2; ++mf)
        af[mf] = *(const bf16x8*)&As[aoff[ks][mf]];
#pragma unroll
      for (int nf = 0; nf < 4; ++nf)
        bfr[nf] = *(const bf16x8*)&Bs[boff[ks][nf]];
#pragma unroll
      for (int mf = 0; mf < 2; ++mf)
#pragma unroll
        for (int nf = 0; nf < 4; ++nf)
          acc[mf][nf] = __builtin_amdgcn_mfma_f32_16x16x32_bf16(af[mf], bfr[nf], acc[mf][nf], 0, 0, 0);
    }
    __syncthreads();
  }
#pragma unroll
  for (int mf = 0; mf < 2; ++mf)
#pragma unroll
    for (int nf = 0; nf < 4; ++nf)
#pragma unroll
      for (int r = 0; r < 4; ++r) {
        int row = bm * 64 + wr * 32 + mf * 16 + lq * 4 + r;
        int col = bn * 128 + wc * 64 + nf * 16 + l15;
        C[(size_t)row * N + col] = acc[mf][nf][r];
      }
}

// ---------------- RoPE + extract heads ----------------
__global__ void rope_kernel(const float* __restrict__ Cq, bf16* __restrict__ qr,
                            bf16* __restrict__ kr, bf16* __restrict__ vt) {
  int idx = blockIdx.x * blockDim.x + threadIdx.x;  // (m, h, p)
  int p = idx & 31;
  int h = (idx >> 5) & 15;
  int m = idx >> 9;
  int s = m & (SEQ - 1);
  int b = m >> 11;
  const float* row = Cq + (size_t)m * H3 + h * 192;
  float q0 = row[2 * p], q1 = row[2 * p + 1];
  float k0 = row[64 + 2 * p], k1 = row[64 + 2 * p + 1];
  float v0 = row[128 + 2 * p], v1 = row[128 + 2 * p + 1];
  float invf = expf(-(float)p * (9.210340371976184f / 32.0f));  // 10000^(-2p/64)
  float fr = (float)s * invf;
  float sn, cs;
  sincosf(fr, &sn, &cs);
  const int bh = b * NHEAD + h;
  size_t o = ((size_t)bh * SEQ + s) * 64 + 2 * p;
  qr[o] = (bf16)((q0 * cs - q1 * sn) * 0.125f);
  qr[o + 1] = (bf16)((q1 * cs + q0 * sn) * 0.125f);
  kr[o] = (bf16)(k0 * cs - k1 * sn); kr[o + 1] = (bf16)(k1 * cs + k0 * sn);
  vt[((size_t)bh * 64 + 2 * p) * SEQ + s] = (bf16)v0;
  vt[((size_t)bh * 64 + 2 * p + 1) * SEQ + s] = (bf16)v1;
}

// ---------------- flash attention: 128-row Q tile, 4 waves x 32 rows ----------------
// ROUND-12 DELTA (parameter change on the verified r9/r10 skeleton): QBLK 64->128.
// Each wave owns 32 Q rows = 2 groups of 16 (g=0,1). K/V re-staging per (b,h)
// halves (16 blocks instead of 32 re-read the 512KB K/V stream); 32 MFMA per
// staged tile (was 16) with B-fragments loaded once, reused for both groups.
// LDS: Kt 16 + Vt 16 + Pl 16 = 48 KiB -> 2 blocks/CU. Grid (16,32)=512=2/CU.
__global__ __launch_bounds__(256, 2)
void attn_kernel(const bf16* __restrict__ qr, const bf16* __restrict__ kr,
                 const bf16* __restrict__ vt, const bf16* __restrict__ maskb,
                 float* __restrict__ ctx) {
  __shared__ bf16 Kt[2][64 * 64];
  __shared__ bf16 Vt[2][64 * 64];
  __shared__ bf16 Pl[4][32 * 64];
  const int tid = threadIdx.x, lane = tid & 63, wid = tid >> 6;
  const int l15 = lane & 15, lq = lane >> 4;
  const int qt = blockIdx.x, bh = blockIdx.y;
  const int b = bh >> 4, hh = bh & 15;
  bf16x8 aq[2][2];
#pragma unroll
  for (int g = 0; g < 2; ++g) {
    const size_t baseQ = ((size_t)bh * SEQ + qt * 128 + wid * 32 + g * 16) * 64;
    aq[g][0] = *(const bf16x8*)&qr[baseQ + (size_t)l15 * 64 + 0 + lq * 8];
    aq[g][1] = *(const bf16x8*)&qr[baseQ + (size_t)l15 * 64 + 32 + lq * 8];
  }
  float mrow[2][4], lrow[2][4];
  f32x4 oacc[2][4] = {};
#pragma unroll
  for (int g = 0; g < 2; ++g)
#pragma unroll
    for (int r = 0; r < 4; ++r) { mrow[g][r] = -1e30f; lrow[g][r] = 0.0f; }
  const int srow = tid >> 3;
  const int schk = (tid & 7) ^ (srow & 7);
  const bf16* kBase = kr + ((size_t)bh * SEQ + srow) * 64 + schk * 8;
  const bf16* vBase = vt + ((size_t)bh * 64 + srow) * SEQ + schk * 8;

#define ASTAGE(bi_, kv_)                                                        \
  do {                                                                          \
    gld_lds16(kBase + (size_t)(kv_) * 64, &Kt[bi_][0] + tid * 8);               \
    gld_lds16(kBase + (size_t)((kv_) + 32) * 64, &Kt[bi_][0] + 2048 + tid * 8); \
    gld_lds16(vBase + (kv_), &Vt[bi_][0] + tid * 8);                            \
    gld_lds16(vBase + (size_t)32 * SEQ + (kv_), &Vt[bi_][0] + 2048 + tid * 8);  \
  } while (0)

  ASTAGE(0, 0);
  WAITVM0();
  BARRIER();
  for (int kv0 = 0; kv0 < SEQ; kv0 += 64) {
    const int cur = (kv0 >> 6) & 1;
    if (kv0 + 64 < SEQ) { ASTAGE(cur ^ 1, kv0 + 64); MEMFENCE(); }
    const bf16* kt = &Kt[cur][0];
    const bf16* vtl = &Vt[cur][0];
    f32x4 sacc[2][4] = {};
    __builtin_amdgcn_s_setprio(1);
#pragma unroll
    for (int k0 = 0; k0 < 2; ++k0) {
#pragma unroll
      for (int nf = 0; nf < 4; ++nf) {
        bf16x8 bk = *(const bf16x8*)&kt[(nf * 16 + l15) * 64 + (((k0 * 4 + lq) ^ (l15 & 7)) << 3)];
#pragma unroll
        for (int g = 0; g < 2; ++g)
          sacc[g][nf] = __builtin_amdgcn_mfma_f32_16x16x32_bf16(aq[g][k0], bk, sacc[g][nf], 0, 0, 0);
      }
    }
    __builtin_amdgcn_s_setprio(0);
#pragma unroll
    for (int g = 0; g < 2; ++g) {
      const int qg0 = qt * 128 + wid * 32 + g * 16 + lq * 4;
#pragma unroll
      for (int nf = 0; nf < 4; ++nf) {
        int kvg = kv0 + nf * 16 + l15;
#pragma unroll
        for (int r = 0; r < 4; ++r)
          sacc[g][nf][r] += (float)maskb[(size_t)(qg0 + r) * SEQ + kvg];
      }
      float fac[4];
#pragma unroll
      for (int r = 0; r < 4; ++r) {
        float v = fmaxf(fmaxf(sacc[g][0][r], sacc[g][1][r]), fmaxf(sacc[g][2][r], sacc[g][3][r]));
        v = fmaxf(v, __shfl_xor(v, 1));
        v = fmaxf(v, __shfl_xor(v, 2));
        v = fmaxf(v, __shfl_xor(v, 4));
        v = fmaxf(v, __shfl_xor(v, 8));
        float mnew = fmaxf(mrow[g][r], v);
        fac[r] = __expf(mrow[g][r] - mnew);
        mrow[g][r] = mnew;
      }
      float rs[4] = {0, 0, 0, 0};
#pragma unroll
      for (int nf = 0; nf < 4; ++nf)
#pragma unroll
        for (int r = 0; r < 4; ++r) {
          float pv = __expf(sacc[g][nf][r] - mrow[g][r]);
          sacc[g][nf][r] = pv;
          rs[r] += pv;
        }
#pragma unroll
      for (int r = 0; r < 4; ++r) {
        float v = rs[r];
        v += __shfl_xor(v, 1); v += __shfl_xor(v, 2);
        v += __shfl_xor(v, 4); v += __shfl_xor(v, 8);
        lrow[g][r] = lrow[g][r] * fac[r] + v;
      }
#pragma unroll
      for (int nf = 0; nf < 4; ++nf)
#pragma unroll
        for (int r = 0; r < 4; ++r) {
          int qrow = g * 16 + lq * 4 + r;
          int col = nf * 16 + l15;
          Pl[wid][qrow * 64 + ((((col >> 3) ^ (qrow & 7))) << 3) + (col & 7)] = (bf16)sacc[g][nf][r];
        }
#pragma unroll
      for (int nf = 0; nf < 4; ++nf)
#pragma unroll
        for (int r = 0; r < 4; ++r)
          oacc[g][nf][r] *= fac[r];
    }
    __builtin_amdgcn_s_setprio(1);
#pragma unroll
    for (int k0 = 0; k0 < 2; ++k0) {
#pragma unroll
      for (int g = 0; g < 2; ++g) {
        bf16x8 ap = *(const bf16x8*)&Pl[wid][(g * 16 + l15) * 64 + (((k0 * 4 + lq) ^ (l15 & 7)) << 3)];
#pragma unroll
        for (int nf = 0; nf < 4; ++nf) {
          bf16x8 bv = *(const bf16x8*)&vtl[(nf * 16 + l15) * 64 + (((k0 * 4 + lq) ^ (l15 & 7)) << 3)];
          oacc[g][nf] = __builtin_amdgcn_mfma_f32_16x16x32_bf16(ap, bv, oacc[g][nf], 0, 0, 0);
        }
      }
    }
    __builtin_amdgcn_s_setprio(0);
    WAITVM0();
    BARRIER();
  }
#undef ASTAGE
#pragma unroll
  for (int g = 0; g < 2; ++g)
#pragma unroll
    for (int nf = 0; nf < 4; ++nf)
#pragma unroll
      for (int r = 0; r < 4; ++r) {
        int row = qt * 128 + wid * 32 + g * 16 + lq * 4 + r;
        int col = hh * 64 + nf * 16 + l15;
        ctx[((size_t)b * SEQ + row) * HID + col] = oacc[g][nf][r] / lrow[g][r];
      }
}

// ---------------- launch ----------------
extern "C" void kernel_launch(void* const* d_in, const int* in_sizes, int n_in,
                              void* d_out, int out_size, void* d_ws, size_t ws_size,
                              hipStream_t stream) {
  const float* qin    = (const float*)d_in[0];
  const float* kin    = (const float*)d_in[1];
  const float* vin    = (const float*)d_in[2];
  const float* mask   = (const float*)d_in[3];
  const float* qkv_bw = (const float*)d_in[4];
  const float* qkv_sw = (const float*)d_in[5];
  const float* qkv_sc = (const float*)d_in[6];
  const float* out_bw = (const float*)d_in[7];
  const float* out_sw = (const float*)d_in[8];
  const float* out_sc = (const float*)d_in[9];
  char* ws = (char*)d_ws;
  bf16* Wq  = (bf16*)(ws + WQ_OFF);
  bf16* Aq  = (bf16*)(ws + AQ_OFF);
  float* Cq = (float*)(ws + CQ_OFF);
  bf16* qr  = (bf16*)(ws + QR_OFF);
  bf16* kr  = (bf16*)(ws + KR_OFF);
  bf16* vt  = (bf16*)(ws + VB_OFF);
  float* ctx = (float*)(ws + CTX_OFF);
  bf16* A2  = (bf16*)(ws + A2_OFF);
  bf16* W2  = (bf16*)(ws + W2_OFF);
  bf16* mb  = (bf16*)(ws + MB_OFF);

  wprep_kernel<<<dim3(H3 / 256, H3), 256, 0, stream>>>(qkv_bw, qkv_sw, qkv_sc, Wq, H3);
  act_qkv_kernel<<<dim3(H3 / 256, MROWS), 256, 0, stream>>>(qin, kin, vin, Aq);
  gemm_kernel<<<dim3(H3 / 128, MROWS / 128), 256, 0, stream>>>(Aq, Wq, Cq, H3, K1DIM);
  maskprep_kernel<<<(SEQ * SEQ) / 1024, 256, 0, stream>>>(mask, mb);   // Wq dead now
  rope_kernel<<<(MROWS * NHEAD * 32) / 256, 256, 0, stream>>>(Cq, qr, kr, vt);
  attn_kernel<<<dim3(SEQ / 128, BATCH * NHEAD), 256, 0, stream>>>(qr, kr, vt, mb, ctx);
  act_out_kernel<<<dim3(HID / 256, MROWS), 256, 0, stream>>>(ctx, A2);
  wprep_kernel<<<dim3(HID / 256, HID), 256, 0, stream>>>(out_bw, out_sw, out_sc, W2, HID);
  gemm2_kernel<<<dim3(HID / 128, MROWS / 64), 256, 0, stream>>>(A2, W2, (float*)d_out, HID, K2DIM);
}

// Round 13
// 1136.129 us; speedup vs baseline: 1.0601x; 1.0601x over previous
//
#include <hip/hip_runtime.h>
#include <hip/hip_bf16.h>
#include <stdint.h>

typedef __bf16 bf16;
typedef __attribute__((ext_vector_type(4))) __bf16 bf16x4;
typedef __attribute__((ext_vector_type(8))) __bf16 bf16x8;
typedef __attribute__((ext_vector_type(4))) float f32x4;

#define DEVI __device__ __forceinline__

// ---------------- constants ----------------
constexpr int BATCH = 2, SEQ = 2048, HID = 1024, NHEAD = 16, HDIM = 64;
constexpr int H3 = 3072;                 // 3*HID
constexpr int MROWS = BATCH * SEQ;       // 4096
constexpr int KEXP = 9;                  // 1 (silu) + 8 spline coefs
constexpr int K1DIM = H3 * KEXP;         // 27648
constexpr int K2DIM = HID * KEXP;        // 9216

// workspace layout (bytes)
constexpr size_t WQ_OFF  = 0;
constexpr size_t AQ_OFF  = 169869312;
constexpr size_t CQ_OFF  = AQ_OFF + 226492416;
constexpr size_t QR_OFF  = CQ_OFF + 50331648;
constexpr size_t KR_OFF  = QR_OFF + 8388608;
constexpr size_t VB_OFF  = KR_OFF + 8388608;
constexpr size_t CTX_OFF = VB_OFF + 8388608;
constexpr size_t A2_OFF  = 0;                       // reuse Wq region (dead after gemm1)
constexpr size_t W2_OFF  = 75497472;
constexpr size_t MB_OFF  = W2_OFF + 18874368;       // bf16 mask (8.4MB), dead-Wq region

DEVI void gld_lds16(const void* g, void* l) {
  __builtin_amdgcn_global_load_lds((const __attribute__((address_space(1))) void*)g,
                                   (__attribute__((address_space(3))) void*)l, 16, 0, 0);
}

#define WAITVM0() asm volatile("s_waitcnt vmcnt(0)" ::: "memory")
#define MEMFENCE() asm volatile("" ::: "memory")
#define BARRIER() do { __builtin_amdgcn_s_barrier(); asm volatile("" ::: "memory"); } while (0)

// silu + cubic B-spline bases on uniform grid h=0.4, knots g[j]=(j-3)*0.4-1, j=0..11
DEVI void silu_bases(float x, float* o9) {
  o9[0] = x / (1.0f + __expf(-x));
  float g[12];
#pragma unroll
  for (int j = 0; j < 12; ++j) g[j] = (float)(j - 3) * 0.4f - 1.0f;
  float b[11];
#pragma unroll
  for (int j = 0; j < 11; ++j) b[j] = (x >= g[j] && x < g[j + 1]) ? 1.0f : 0.0f;
#pragma unroll
  for (int k = 1; k <= 3; ++k) {
    const float inv = (k == 1) ? 2.5f : (k == 2) ? 1.25f : (1.0f / 1.2f);
#pragma unroll
    for (int j = 0; j + k < 11; ++j) {
      b[j] = (x - g[j]) * inv * b[j] + (g[j + k + 1] - x) * inv * b[j + 1];
    }
  }
#pragma unroll
  for (int c = 0; c < 8; ++c) o9[1 + c] = b[c];
}

// ---------------- weight repack (LDS-coalesced) ----------------
__global__ __launch_bounds__(256)
void wprep_kernel(const float* __restrict__ bw, const float* __restrict__ sw,
                  const float* __restrict__ sc, bf16* __restrict__ W, int KK) {
  __shared__ bf16 buf[256 * KEXP];
  const int tid = threadIdx.x;
  const int n = blockIdx.y;
  const int i0 = blockIdx.x * 256;
  const size_t idx = (size_t)n * KK + i0 + tid;
  float base = bw[idx];
  float scal = sc[idx];
  const float4* sp = (const float4*)(sw + idx * 8);
  float4 s0 = sp[0], s1 = sp[1];
  bf16* o = buf + tid * KEXP;
  o[0] = (bf16)base;
  o[1] = (bf16)(s0.x * scal); o[2] = (bf16)(s0.y * scal);
  o[3] = (bf16)(s0.z * scal); o[4] = (bf16)(s0.w * scal);
  o[5] = (bf16)(s1.x * scal); o[6] = (bf16)(s1.y * scal);
  o[7] = (bf16)(s1.z * scal); o[8] = (bf16)(s1.w * scal);
  __syncthreads();
  bf16* dst = W + (size_t)n * KK * KEXP + (size_t)i0 * KEXP;
#pragma unroll
  for (int j = tid; j < 256 * KEXP / 8; j += 256)
    *(bf16x8*)(dst + j * 8) = *(const bf16x8*)(buf + j * 8);
}

// ---------------- activation expansion, LDS-coalesced ----------------
__global__ __launch_bounds__(256)
void act_qkv_kernel(const float* __restrict__ qin, const float* __restrict__ kin,
                    const float* __restrict__ vin, bf16* __restrict__ A) {
  __shared__ bf16 buf[256 * KEXP];
  const int tid = threadIdx.x;
  const int m = blockIdx.y;
  const int i0 = blockIdx.x * 256;
  const int i = i0 + tid;
  const int which = i >> 10, off = i & 1023;
  const float* src = (which == 0) ? qin : (which == 1) ? kin : vin;
  float x = src[(size_t)m * HID + off];
  float o9[9];
  silu_bases(x, o9);
  bf16* o = buf + tid * KEXP;
#pragma unroll
  for (int c = 0; c < 9; ++c) o[c] = (bf16)o9[c];
  __syncthreads();
  bf16* dst = A + (size_t)m * K1DIM + (size_t)i0 * KEXP;
#pragma unroll
  for (int j = tid; j < 256 * KEXP / 8; j += 256)
    *(bf16x8*)(dst + j * 8) = *(const bf16x8*)(buf + j * 8);
}

__global__ __launch_bounds__(256)
void act_out_kernel(const float* __restrict__ ctx, bf16* __restrict__ A) {
  __shared__ bf16 buf[256 * KEXP];
  const int tid = threadIdx.x;
  const int m = blockIdx.y;
  const int i0 = blockIdx.x * 256;
  float x = ctx[(size_t)m * HID + i0 + tid];
  float o9[9];
  silu_bases(x, o9);
  bf16* o = buf + tid * KEXP;
#pragma unroll
  for (int c = 0; c < 9; ++c) o[c] = (bf16)o9[c];
  __syncthreads();
  bf16* dst = A + (size_t)m * K2DIM + (size_t)i0 * KEXP;
#pragma unroll
  for (int j = tid; j < 256 * KEXP / 8; j += 256)
    *(bf16x8*)(dst + j * 8) = *(const bf16x8*)(buf + j * 8);
}

// ---------------- mask fp32 -> bf16 ----------------
__global__ __launch_bounds__(256)
void maskprep_kernel(const float* __restrict__ m, bf16* __restrict__ mb) {
  int i = (blockIdx.x * 256 + threadIdx.x) * 4;
  float4 v = *(const float4*)(m + i);
  bf16x4 o = { (bf16)v.x, (bf16)v.y, (bf16)v.z, (bf16)v.w };
  *(bf16x4*)(mb + i) = o;
}

// ---------------- gemm1: 128x128 tile, BK=64, 8 WAVES (512 threads) ----------------
// ROUND-13 DELTA (thread-mapping change on the verified r4 skeleton; tile, LDS,
// sync structure, swizzle ALL unchanged): 256->512 threads. Grid stays 768 = 3
// blocks/CU, but waves/CU 12 -> 24 (6/SIMD) -> better hiding of the 2-phase
// barrier drain. 8 waves as 2M x 4N; per-wave 64x32 = 4x2 frags, 8 MFMA/ks.
// Staging: 512 threads x 2 rounds x (A+B) = 4 gld_lds/thread.
__global__ __launch_bounds__(512, 6)
void gemm_kernel(const bf16* __restrict__ A, const bf16* __restrict__ Bw,
                 float* __restrict__ C, int N, int K) {
  __shared__ bf16 As[128 * 64];
  __shared__ bf16 Bs[128 * 64];
  const int tid = threadIdx.x;
  const int lane = tid & 63;
  const int l15 = lane & 15, lq = lane >> 4;
  const int wid = tid >> 6;                 // 0..7
  const int wm = (wid >> 2) * 64;           // M half
  const int wn = (wid & 3) * 32;            // N quarter
  const int bm = blockIdx.y, bn = blockIdx.x;
  f32x4 acc[4][2] = {};
  const int srow = tid >> 3;                // row 0..63 (round r adds 64)
  const int schk = (tid & 7) ^ (srow & 7);  // pre-swizzled source chunk (64%8==0 -> same both rounds)
  const bf16* aB = A + (size_t)(bm * 128 + srow) * K + schk * 8;
  const bf16* bB = Bw + (size_t)(bn * 128 + srow) * K + schk * 8;

  int aoff[2][4], boff[2][2];
#pragma unroll
  for (int ks = 0; ks < 2; ++ks) {
#pragma unroll
    for (int f = 0; f < 4; ++f) {
      int arow = wm + f * 16 + l15;
      aoff[ks][f] = arow * 64 + (((ks * 4 + lq) ^ (arow & 7)) * 8);
    }
#pragma unroll
    for (int f = 0; f < 2; ++f) {
      int brow = wn + f * 16 + l15;
      boff[ks][f] = brow * 64 + (((ks * 4 + lq) ^ (brow & 7)) * 8);
    }
  }

  for (int kt = 0; kt < K; kt += 64) {
#pragma unroll
    for (int r = 0; r < 2; ++r) {
      gld_lds16(aB + (size_t)(r * 64) * K + kt, As + r * 4096 + tid * 8);
      gld_lds16(bB + (size_t)(r * 64) * K + kt, Bs + r * 4096 + tid * 8);
    }
    __syncthreads();
#pragma unroll
    for (int ks = 0; ks < 2; ++ks) {
      bf16x8 af[4], bfr[2];
#pragma unroll
      for (int mf = 0; mf < 4; ++mf)
        af[mf] = *(const bf16x8*)&As[aoff[ks][mf]];
#pragma unroll
      for (int nf = 0; nf < 2; ++nf)
        bfr[nf] = *(const bf16x8*)&Bs[boff[ks][nf]];
#pragma unroll
      for (int mf = 0; mf < 4; ++mf)
#pragma unroll
        for (int nf = 0; nf < 2; ++nf)
          acc[mf][nf] = __builtin_amdgcn_mfma_f32_16x16x32_bf16(af[mf], bfr[nf], acc[mf][nf], 0, 0, 0);
    }
    __syncthreads();
  }
#pragma unroll
  for (int mf = 0; mf < 4; ++mf)
#pragma unroll
    for (int nf = 0; nf < 2; ++nf)
#pragma unroll
      for (int r = 0; r < 4; ++r) {
        int row = bm * 128 + wm + mf * 16 + lq * 4 + r;
        int col = bn * 128 + wn + nf * 16 + l15;
        C[(size_t)row * N + col] = acc[mf][nf][r];
      }
}

// ---------------- gemm2: 64x128 tile (verified round 10) ----------------
__global__ __launch_bounds__(256, 2)
void gemm2_kernel(const bf16* __restrict__ A, const bf16* __restrict__ Bw,
                  float* __restrict__ C, int N, int K) {
  __shared__ bf16 As[64 * 64];       // 8 KiB
  __shared__ bf16 Bs[128 * 64];      // 16 KiB
  const int tid = threadIdx.x;
  const int lane = tid & 63;
  const int l15 = lane & 15, lq = lane >> 4;
  const int wid = tid >> 6;
  const int wr = wid >> 1, wc = wid & 1;   // wave tile 32(M) x 64(N)
  const int bm = blockIdx.y, bn = blockIdx.x;
  f32x4 acc[2][4] = {};
  const int srow = tid >> 3;
  const int schk = (tid & 7) ^ (srow & 7);
  const bf16* aB = A + (size_t)(bm * 64 + srow) * K + schk * 8;
  const bf16* bB = Bw + (size_t)(bn * 128 + srow) * K + schk * 8;

  int aoff[2][2], boff[2][4];
#pragma unroll
  for (int ks = 0; ks < 2; ++ks) {
#pragma unroll
    for (int f = 0; f < 2; ++f) {
      int arow = wr * 32 + f * 16 + l15;
      aoff[ks][f] = arow * 64 + (((ks * 4 + lq) ^ (arow & 7)) * 8);
    }
#pragma unroll
    for (int f = 0; f < 4; ++f) {
      int brow = wc * 64 + f * 16 + l15;
      boff[ks][f] = brow * 64 + (((ks * 4 + lq) ^ (brow & 7)) * 8);
    }
  }

  for (int kt = 0; kt < K; kt += 64) {
#pragma unroll
    for (int r = 0; r < 2; ++r)
      gld_lds16(aB + (size_t)(r * 32) * K + kt, As + r * 2048 + tid * 8);
#pragma unroll
    for (int r = 0; r < 4; ++r)
      gld_lds16(bB + (size_t)(r * 32) * K + kt, Bs + r * 2048 + tid * 8);
    __syncthreads();
#pragma unroll
    for (int ks = 0; ks < 2; ++ks) {
      bf16x8 af[2], bfr[4];
#pragma unroll
      for (int mf = 0; mf < 2; ++mf)
        af[mf] = *(const bf16x8*)&As[aoff[ks][mf]];
#pragma unroll
      for (int nf = 0; nf < 4; ++nf)
        bfr[nf] = *(const bf16x8*)&Bs[boff[ks][nf]];
#pragma unroll
      for (int mf = 0; mf < 2; ++mf)
#pragma unroll
        for (int nf = 0; nf < 4; ++nf)
          acc[mf][nf] = __builtin_amdgcn_mfma_f32_16x16x32_bf16(af[mf], bfr[nf], acc[mf][nf], 0, 0, 0);
    }
    __syncthreads();
  }
#pragma unroll
  for (int mf = 0; mf < 2; ++mf)
#pragma unroll
    for (int nf = 0; nf < 4; ++nf)
#pragma unroll
      for (int r = 0; r < 4; ++r) {
        int row = bm * 64 + wr * 32 + mf * 16 + lq * 4 + r;
        int col = bn * 128 + wc * 64 + nf * 16 + l15;
        C[(size_t)row * N + col] = acc[mf][nf][r];
      }
}

// ---------------- RoPE + extract heads ----------------
__global__ void rope_kernel(const float* __restrict__ Cq, bf16* __restrict__ qr,
                            bf16* __restrict__ kr, bf16* __restrict__ vt) {
  int idx = blockIdx.x * blockDim.x + threadIdx.x;  // (m, h, p)
  int p = idx & 31;
  int h = (idx >> 5) & 15;
  int m = idx >> 9;
  int s = m & (SEQ - 1);
  int b = m >> 11;
  const float* row = Cq + (size_t)m * H3 + h * 192;
  float q0 = row[2 * p], q1 = row[2 * p + 1];
  float k0 = row[64 + 2 * p], k1 = row[64 + 2 * p + 1];
  float v0 = row[128 + 2 * p], v1 = row[128 + 2 * p + 1];
  float invf = expf(-(float)p * (9.210340371976184f / 32.0f));  // 10000^(-2p/64)
  float fr = (float)s * invf;
  float sn, cs;
  sincosf(fr, &sn, &cs);
  const int bh = b * NHEAD + h;
  size_t o = ((size_t)bh * SEQ + s) * 64 + 2 * p;
  qr[o] = (bf16)((q0 * cs - q1 * sn) * 0.125f);
  qr[o + 1] = (bf16)((q1 * cs + q0 * sn) * 0.125f);
  kr[o] = (bf16)(k0 * cs - k1 * sn); kr[o + 1] = (bf16)(k1 * cs + k0 * sn);
  vt[((size_t)bh * 64 + 2 * p) * SEQ + s] = (bf16)v0;
  vt[((size_t)bh * 64 + 2 * p + 1) * SEQ + s] = (bf16)v1;
}

// ---------------- flash attention (ROUND-10 EXACT CONFIG — measured best) ----------
// QBLK=64. r12's QBLK=128 regressed (+86us: VGPR/LDS growth cut occupancy).
__global__ __launch_bounds__(256, 2)
void attn_kernel(const bf16* __restrict__ qr, const bf16* __restrict__ kr,
                 const bf16* __restrict__ vt, const bf16* __restrict__ maskb,
                 float* __restrict__ ctx) {
  __shared__ bf16 Kt[2][64 * 64];
  __shared__ bf16 Vt[2][64 * 64];
  __shared__ bf16 Pl[4][16 * 64];
  const int tid = threadIdx.x, lane = tid & 63, wid = tid >> 6;
  const int l15 = lane & 15, lq = lane >> 4;
  const int qt = blockIdx.x, bh = blockIdx.y;
  const int b = bh >> 4, hh = bh & 15;
  const size_t baseQ = ((size_t)bh * SEQ + qt * 64 + wid * 16) * 64;
  bf16x8 aq[2];
  aq[0] = *(const bf16x8*)&qr[baseQ + (size_t)l15 * 64 + 0 + lq * 8];
  aq[1] = *(const bf16x8*)&qr[baseQ + (size_t)l15 * 64 + 32 + lq * 8];
  float mrow[4], lrow[4];
  f32x4 oacc[4] = {};
#pragma unroll
  for (int r = 0; r < 4; ++r) { mrow[r] = -1e30f; lrow[r] = 0.0f; }
  const int srow = tid >> 3;
  const int schk = (tid & 7) ^ (srow & 7);
  const bf16* kBase = kr + ((size_t)bh * SEQ + srow) * 64 + schk * 8;
  const bf16* vBase = vt + ((size_t)bh * 64 + srow) * SEQ + schk * 8;

#define ASTAGE(bi_, kv_)                                                        \
  do {                                                                          \
    gld_lds16(kBase + (size_t)(kv_) * 64, &Kt[bi_][0] + tid * 8);               \
    gld_lds16(kBase + (size_t)((kv_) + 32) * 64, &Kt[bi_][0] + 2048 + tid * 8); \
    gld_lds16(vBase + (kv_), &Vt[bi_][0] + tid * 8);                            \
    gld_lds16(vBase + (size_t)32 * SEQ + (kv_), &Vt[bi_][0] + 2048 + tid * 8);  \
  } while (0)

  ASTAGE(0, 0);
  WAITVM0();
  BARRIER();
  for (int kv0 = 0; kv0 < SEQ; kv0 += 64) {
    const int cur = (kv0 >> 6) & 1;
    if (kv0 + 64 < SEQ) { ASTAGE(cur ^ 1, kv0 + 64); MEMFENCE(); }
    const bf16* kt = &Kt[cur][0];
    const bf16* vtl = &Vt[cur][0];
    f32x4 sacc[4] = {};
    __builtin_amdgcn_s_setprio(1);
#pragma unroll
    for (int k0 = 0; k0 < 2; ++k0) {
#pragma unroll
      for (int nf = 0; nf < 4; ++nf) {
        bf16x8 bk = *(const bf16x8*)&kt[(nf * 16 + l15) * 64 + (((k0 * 4 + lq) ^ (l15 & 7)) << 3)];
        sacc[nf] = __builtin_amdgcn_mfma_f32_16x16x32_bf16(aq[k0], bk, sacc[nf], 0, 0, 0);
      }
    }
    __builtin_amdgcn_s_setprio(0);
    const int qg0 = qt * 64 + wid * 16 + lq * 4;
#pragma unroll
    for (int nf = 0; nf < 4; ++nf) {
      int kvg = kv0 + nf * 16 + l15;
#pragma unroll
      for (int r = 0; r < 4; ++r)
        sacc[nf][r] += (float)maskb[(size_t)(qg0 + r) * SEQ + kvg];
    }
    float fac[4];
#pragma unroll
    for (int r = 0; r < 4; ++r) {
      float v = fmaxf(fmaxf(sacc[0][r], sacc[1][r]), fmaxf(sacc[2][r], sacc[3][r]));
      v = fmaxf(v, __shfl_xor(v, 1));
      v = fmaxf(v, __shfl_xor(v, 2));
      v = fmaxf(v, __shfl_xor(v, 4));
      v = fmaxf(v, __shfl_xor(v, 8));
      float mnew = fmaxf(mrow[r], v);
      fac[r] = __expf(mrow[r] - mnew);
      mrow[r] = mnew;
    }
    float rs[4] = {0, 0, 0, 0};
#pragma unroll
    for (int nf = 0; nf < 4; ++nf)
#pragma unroll
      for (int r = 0; r < 4; ++r) {
        float pv = __expf(sacc[nf][r] - mrow[r]);
        sacc[nf][r] = pv;
        rs[r] += pv;
      }
#pragma unroll
    for (int r = 0; r < 4; ++r) {
      float v = rs[r];
      v += __shfl_xor(v, 1); v += __shfl_xor(v, 2);
      v += __shfl_xor(v, 4); v += __shfl_xor(v, 8);
      lrow[r] = lrow[r] * fac[r] + v;
    }
#pragma unroll
    for (int nf = 0; nf < 4; ++nf)
#pragma unroll
      for (int r = 0; r < 4; ++r) {
        int qrow = lq * 4 + r;
        int col = nf * 16 + l15;
        Pl[wid][qrow * 64 + ((((col >> 3) ^ (qrow & 7))) << 3) + (col & 7)] = (bf16)sacc[nf][r];
      }
#pragma unroll
    for (int nf = 0; nf < 4; ++nf)
#pragma unroll
      for (int r = 0; r < 4; ++r)
        oacc[nf][r] *= fac[r];
    __builtin_amdgcn_s_setprio(1);
#pragma unroll
    for (int k0 = 0; k0 < 2; ++k0) {
      bf16x8 ap = *(const bf16x8*)&Pl[wid][l15 * 64 + (((k0 * 4 + lq) ^ (l15 & 7)) << 3)];
#pragma unroll
      for (int nf = 0; nf < 4; ++nf) {
        bf16x8 bv = *(const bf16x8*)&vtl[(nf * 16 + l15) * 64 + (((k0 * 4 + lq) ^ (l15 & 7)) << 3)];
        oacc[nf] = __builtin_amdgcn_mfma_f32_16x16x32_bf16(ap, bv, oacc[nf], 0, 0, 0);
      }
    }
    __builtin_amdgcn_s_setprio(0);
    WAITVM0();
    BARRIER();
  }
#undef ASTAGE
#pragma unroll
  for (int nf = 0; nf < 4; ++nf)
#pragma unroll
    for (int r = 0; r < 4; ++r) {
      int row = qt * 64 + wid * 16 + lq * 4 + r;
      int col = hh * 64 + nf * 16 + l15;
      ctx[((size_t)b * SEQ + row) * HID + col] = oacc[nf][r] / lrow[r];
    }
}

// ---------------- launch ----------------
extern "C" void kernel_launch(void* const* d_in, const int* in_sizes, int n_in,
                              void* d_out, int out_size, void* d_ws, size_t ws_size,
                              hipStream_t stream) {
  const float* qin    = (const float*)d_in[0];
  const float* kin    = (const float*)d_in[1];
  const float* vin    = (const float*)d_in[2];
  const float* mask   = (const float*)d_in[3];
  const float* qkv_bw = (const float*)d_in[4];
  const float* qkv_sw = (const float*)d_in[5];
  const float* qkv_sc = (const float*)d_in[6];
  const float* out_bw = (const float*)d_in[7];
  const float* out_sw = (const float*)d_in[8];
  const float* out_sc = (const float*)d_in[9];
  char* ws = (char*)d_ws;
  bf16* Wq  = (bf16*)(ws + WQ_OFF);
  bf16* Aq  = (bf16*)(ws + AQ_OFF);
  float* Cq = (float*)(ws + CQ_OFF);
  bf16* qr  = (bf16*)(ws + QR_OFF);
  bf16* kr  = (bf16*)(ws + KR_OFF);
  bf16* vt  = (bf16*)(ws + VB_OFF);
  float* ctx = (float*)(ws + CTX_OFF);
  bf16* A2  = (bf16*)(ws + A2_OFF);
  bf16* W2  = (bf16*)(ws + W2_OFF);
  bf16* mb  = (bf16*)(ws + MB_OFF);

  wprep_kernel<<<dim3(H3 / 256, H3), 256, 0, stream>>>(qkv_bw, qkv_sw, qkv_sc, Wq, H3);
  act_qkv_kernel<<<dim3(H3 / 256, MROWS), 256, 0, stream>>>(qin, kin, vin, Aq);
  gemm_kernel<<<dim3(H3 / 128, MROWS / 128), 512, 0, stream>>>(Aq, Wq, Cq, H3, K1DIM);
  maskprep_kernel<<<(SEQ * SEQ) / 1024, 256, 0, stream>>>(mask, mb);   // Wq dead now
  rope_kernel<<<(MROWS * NHEAD * 32) / 256, 256, 0, stream>>>(Cq, qr, kr, vt);
  attn_kernel<<<dim3(SEQ / 64, BATCH * NHEAD), 256, 0, stream>>>(qr, kr, vt, mb, ctx);
  act_out_kernel<<<dim3(HID / 256, MROWS), 256, 0, stream>>>(ctx, A2);
  wprep_kernel<<<dim3(HID / 256, HID), 256, 0, stream>>>(out_bw, out_sw, out_sc, W2, HID);
  gemm2_kernel<<<dim3(HID / 128, MROWS / 64), 256, 0, stream>>>(A2, W2, (float*)d_out, HID, K2DIM);
}

// Round 14
// 1117.362 us; speedup vs baseline: 1.0779x; 1.0168x over previous
//
#include <hip/hip_runtime.h>
#include <hip/hip_bf16.h>
#include <stdint.h>

typedef __bf16 bf16;
typedef __attribute__((ext_vector_type(4))) __bf16 bf16x4;
typedef __attribute__((ext_vector_type(8))) __bf16 bf16x8;
typedef __attribute__((ext_vector_type(4))) float f32x4;

#define DEVI __device__ __forceinline__

// ---------------- constants ----------------
constexpr int BATCH = 2, SEQ = 2048, HID = 1024, NHEAD = 16, HDIM = 64;
constexpr int H3 = 3072;                 // 3*HID
constexpr int MROWS = BATCH * SEQ;       // 4096
constexpr int KEXP = 9;                  // 1 (silu) + 8 spline coefs
constexpr int K1DIM = H3 * KEXP;         // 27648
constexpr int K2DIM = HID * KEXP;        // 9216

// workspace layout (bytes)
constexpr size_t WQ_OFF  = 0;
constexpr size_t AQ_OFF  = 169869312;
constexpr size_t CQ_OFF  = AQ_OFF + 226492416;      // ex-Cq region (free): vrow + tcs
constexpr size_t VR_OFF  = CQ_OFF;                  // vrow (b,h,s,d) bf16, 8.4 MB
constexpr size_t TC_OFF  = CQ_OFF + 16777216;       // trig table float2[2048][32], 512 KB
constexpr size_t QR_OFF  = CQ_OFF + 50331648;
constexpr size_t KR_OFF  = QR_OFF + 8388608;
constexpr size_t VB_OFF  = KR_OFF + 8388608;
constexpr size_t CTX_OFF = VB_OFF + 8388608;
constexpr size_t A2_OFF  = 0;                       // reuse Wq region (dead after gemm1)
constexpr size_t W2_OFF  = 75497472;
constexpr size_t MB_OFF  = W2_OFF + 18874368;       // bf16 mask (8.4MB), dead-Wq region

DEVI void gld_lds16(const void* g, void* l) {
  __builtin_amdgcn_global_load_lds((const __attribute__((address_space(1))) void*)g,
                                   (__attribute__((address_space(3))) void*)l, 16, 0, 0);
}

#define WAITVM0() asm volatile("s_waitcnt vmcnt(0)" ::: "memory")
#define MEMFENCE() asm volatile("" ::: "memory")
#define BARRIER() do { __builtin_amdgcn_s_barrier(); asm volatile("" ::: "memory"); } while (0)

// silu + cubic B-spline bases on uniform grid h=0.4, knots g[j]=(j-3)*0.4-1, j=0..11
DEVI void silu_bases(float x, float* o9) {
  o9[0] = x / (1.0f + __expf(-x));
  float g[12];
#pragma unroll
  for (int j = 0; j < 12; ++j) g[j] = (float)(j - 3) * 0.4f - 1.0f;
  float b[11];
#pragma unroll
  for (int j = 0; j < 11; ++j) b[j] = (x >= g[j] && x < g[j + 1]) ? 1.0f : 0.0f;
#pragma unroll
  for (int k = 1; k <= 3; ++k) {
    const float inv = (k == 1) ? 2.5f : (k == 2) ? 1.25f : (1.0f / 1.2f);
#pragma unroll
    for (int j = 0; j + k < 11; ++j) {
      b[j] = (x - g[j]) * inv * b[j] + (g[j + k + 1] - x) * inv * b[j + 1];
    }
  }
#pragma unroll
  for (int c = 0; c < 8; ++c) o9[1 + c] = b[c];
}

// ---------------- trig table: tcs[s*32+p] = (cos(s*invf_p), sin(s*invf_p)) ----------------
__global__ __launch_bounds__(256)
void tprep_kernel(float2* __restrict__ tcs) {
  int idx = blockIdx.x * 256 + threadIdx.x;   // 65536 = 2048 x 32
  int s = idx >> 5, p = idx & 31;
  float invf = __expf(-(float)p * (9.210340371976184f / 32.0f));  // 10000^(-2p/64)
  float sn, cs;
  __sincosf((float)s * invf, &sn, &cs);
  tcs[idx] = make_float2(cs, sn);
}

// ---------------- weight repack (LDS-coalesced) ----------------
__global__ __launch_bounds__(256)
void wprep_kernel(const float* __restrict__ bw, const float* __restrict__ sw,
                  const float* __restrict__ sc, bf16* __restrict__ W, int KK) {
  __shared__ bf16 buf[256 * KEXP];
  const int tid = threadIdx.x;
  const int n = blockIdx.y;
  const int i0 = blockIdx.x * 256;
  const size_t idx = (size_t)n * KK + i0 + tid;
  float base = bw[idx];
  float scal = sc[idx];
  const float4* sp = (const float4*)(sw + idx * 8);
  float4 s0 = sp[0], s1 = sp[1];
  bf16* o = buf + tid * KEXP;
  o[0] = (bf16)base;
  o[1] = (bf16)(s0.x * scal); o[2] = (bf16)(s0.y * scal);
  o[3] = (bf16)(s0.z * scal); o[4] = (bf16)(s0.w * scal);
  o[5] = (bf16)(s1.x * scal); o[6] = (bf16)(s1.y * scal);
  o[7] = (bf16)(s1.z * scal); o[8] = (bf16)(s1.w * scal);
  __syncthreads();
  bf16* dst = W + (size_t)n * KK * KEXP + (size_t)i0 * KEXP;
#pragma unroll
  for (int j = tid; j < 256 * KEXP / 8; j += 256)
    *(bf16x8*)(dst + j * 8) = *(const bf16x8*)(buf + j * 8);
}

// ---------------- activation expansion, LDS-coalesced ----------------
__global__ __launch_bounds__(256)
void act_qkv_kernel(const float* __restrict__ qin, const float* __restrict__ kin,
                    const float* __restrict__ vin, bf16* __restrict__ A) {
  __shared__ bf16 buf[256 * KEXP];
  const int tid = threadIdx.x;
  const int m = blockIdx.y;
  const int i0 = blockIdx.x * 256;
  const int i = i0 + tid;
  const int which = i >> 10, off = i & 1023;
  const float* src = (which == 0) ? qin : (which == 1) ? kin : vin;
  float x = src[(size_t)m * HID + off];
  float o9[9];
  silu_bases(x, o9);
  bf16* o = buf + tid * KEXP;
#pragma unroll
  for (int c = 0; c < 9; ++c) o[c] = (bf16)o9[c];
  __syncthreads();
  bf16* dst = A + (size_t)m * K1DIM + (size_t)i0 * KEXP;
#pragma unroll
  for (int j = tid; j < 256 * KEXP / 8; j += 256)
    *(bf16x8*)(dst + j * 8) = *(const bf16x8*)(buf + j * 8);
}

__global__ __launch_bounds__(256)
void act_out_kernel(const float* __restrict__ ctx, bf16* __restrict__ A) {
  __shared__ bf16 buf[256 * KEXP];
  const int tid = threadIdx.x;
  const int m = blockIdx.y;
  const int i0 = blockIdx.x * 256;
  float x = ctx[(size_t)m * HID + i0 + tid];
  float o9[9];
  silu_bases(x, o9);
  bf16* o = buf + tid * KEXP;
#pragma unroll
  for (int c = 0; c < 9; ++c) o[c] = (bf16)o9[c];
  __syncthreads();
  bf16* dst = A + (size_t)m * K2DIM + (size_t)i0 * KEXP;
#pragma unroll
  for (int j = tid; j < 256 * KEXP / 8; j += 256)
    *(bf16x8*)(dst + j * 8) = *(const bf16x8*)(buf + j * 8);
}

// ---------------- mask fp32 -> bf16 ----------------
__global__ __launch_bounds__(256)
void maskprep_kernel(const float* __restrict__ m, bf16* __restrict__ mb) {
  int i = (blockIdx.x * 256 + threadIdx.x) * 4;
  float4 v = *(const float4*)(m + i);
  bf16x4 o = { (bf16)v.x, (bf16)v.y, (bf16)v.z, (bf16)v.w };
  *(bf16x4*)(mb + i) = o;
}

// ---------------- gemm1: 128x128 tile (r4 exact config) + FUSED RoPE EPILOGUE ----------
// Main loop identical to the measured-best r4/r10 structure (690us, MfmaUtil 45%,
// conflicts 0; memory-system-bound — r13 proved invariance to occupancy).
// ROUND-14 DELTA: epilogue applies RoPE and writes q/k/v bf16 directly (no Cq):
//   pair value via __shfl_xor(val,1) (cols 2p/2p+1 sit in adjacent l15 lanes);
//   cos/sin from the precomputed fp32 table (no per-element sincosf);
//   branch q/k/v is uniform per 16-lane group (192 and 64 are multiples of 16).
__global__ __launch_bounds__(256, 2)
void gemm1_kernel(const bf16* __restrict__ A, const bf16* __restrict__ Bw,
                  bf16* __restrict__ qr, bf16* __restrict__ kr,
                  bf16* __restrict__ vrow, const float2* __restrict__ tcs, int K) {
  __shared__ bf16 As[128 * 64];
  __shared__ bf16 Bs[128 * 64];
  const int tid = threadIdx.x;
  const int lane = tid & 63;
  const int l15 = lane & 15, lq = lane >> 4;
  const int wid = tid >> 6;
  const int wm = (wid >> 1) * 64, wn = (wid & 1) * 64;
  const int bm = blockIdx.y, bn = blockIdx.x;
  f32x4 acc[4][4] = {};
  const int srow = tid >> 3;
  const int schk = (tid & 7) ^ (srow & 7);
  const bf16* aB = A + (size_t)(bm * 128 + srow) * K + schk * 8;
  const bf16* bB = Bw + (size_t)(bn * 128 + srow) * K + schk * 8;

  int aoff[2][4], boff[2][4];
#pragma unroll
  for (int ks = 0; ks < 2; ++ks) {
#pragma unroll
    for (int f = 0; f < 4; ++f) {
      int arow = wm + f * 16 + l15;
      int brow = wn + f * 16 + l15;
      aoff[ks][f] = arow * 64 + (((ks * 4 + lq) ^ (arow & 7)) * 8);
      boff[ks][f] = brow * 64 + (((ks * 4 + lq) ^ (brow & 7)) * 8);
    }
  }

  for (int kt = 0; kt < K; kt += 64) {
#pragma unroll
    for (int r = 0; r < 4; ++r) {
      gld_lds16(aB + (size_t)(r * 32) * K + kt, As + r * 2048 + tid * 8);
      gld_lds16(bB + (size_t)(r * 32) * K + kt, Bs + r * 2048 + tid * 8);
    }
    __syncthreads();
#pragma unroll
    for (int ks = 0; ks < 2; ++ks) {
      bf16x8 af[4], bfr[4];
#pragma unroll
      for (int mf = 0; mf < 4; ++mf)
        af[mf] = *(const bf16x8*)&As[aoff[ks][mf]];
#pragma unroll
      for (int nf = 0; nf < 4; ++nf)
        bfr[nf] = *(const bf16x8*)&Bs[boff[ks][nf]];
#pragma unroll
      for (int mf = 0; mf < 4; ++mf)
#pragma unroll
        for (int nf = 0; nf < 4; ++nf)
          acc[mf][nf] = __builtin_amdgcn_mfma_f32_16x16x32_bf16(af[mf], bfr[nf], acc[mf][nf], 0, 0, 0);
    }
    __syncthreads();
  }

  // ---- fused RoPE epilogue ----
#pragma unroll
  for (int mf = 0; mf < 4; ++mf)
#pragma unroll
    for (int nf = 0; nf < 4; ++nf)
#pragma unroll
      for (int rr = 0; rr < 4; ++rr) {
        int row = bm * 128 + wm + mf * 16 + lq * 4 + rr;
        int col = bn * 128 + wn + nf * 16 + l15;
        int s = row & (SEQ - 1);
        int bb = row >> 11;
        int h = col / 192;
        int r2 = col - h * 192;
        int bh = bb * NHEAD + h;
        float val = acc[mf][nf][rr];
        float par = __shfl_xor(val, 1);
        if (r2 < 128) {
          int d = r2 & 63;
          float2 cz = tcs[s * 32 + (d >> 1)];
          float o = (col & 1) ? (val * cz.x + par * cz.y)     // odd col: x1*cos + x0*sin
                              : (val * cz.x - par * cz.y);    // even col: x0*cos - x1*sin
          if (r2 < 64) qr[((size_t)bh * SEQ + s) * 64 + d] = (bf16)(o * 0.125f);
          else         kr[((size_t)bh * SEQ + s) * 64 + d] = (bf16)o;
        } else {
          vrow[((size_t)bh * SEQ + s) * 64 + (r2 - 128)] = (bf16)val;
        }
      }
}

// ---------------- vrow (b,h,s,d) -> vt (b,h,d,s) transpose ----------------
__global__ __launch_bounds__(256)
void vtrans_kernel(const bf16* __restrict__ vrow, bf16* __restrict__ vt) {
  __shared__ bf16 t[64][72];   // +8 pad
  const int tid = threadIdx.x;
  const int st = blockIdx.x, bh = blockIdx.y;
  const size_t base = ((size_t)bh * SEQ + st * 64) * 64;
#pragma unroll
  for (int r = 0; r < 2; ++r) {
    int row = r * 32 + (tid >> 3);
    int c8 = (tid & 7) * 8;
    *(bf16x8*)&t[row][c8] = *(const bf16x8*)&vrow[base + (size_t)row * 64 + c8];
  }
  __syncthreads();
  const int d = tid >> 2;
  const int s0 = (tid & 3) * 16;
  bf16 tmp[16];
#pragma unroll
  for (int e = 0; e < 16; ++e) tmp[e] = t[s0 + e][d];
  bf16* dst = vt + ((size_t)(bh * 64 + d)) * SEQ + st * 64 + s0;
  *(bf16x8*)dst = *(bf16x8*)&tmp[0];
  *(bf16x8*)(dst + 8) = *(bf16x8*)&tmp[8];
}

// ---------------- gemm2: 64x128 tile (verified round 10) ----------------
__global__ __launch_bounds__(256, 2)
void gemm2_kernel(const bf16* __restrict__ A, const bf16* __restrict__ Bw,
                  float* __restrict__ C, int N, int K) {
  __shared__ bf16 As[64 * 64];       // 8 KiB
  __shared__ bf16 Bs[128 * 64];      // 16 KiB
  const int tid = threadIdx.x;
  const int lane = tid & 63;
  const int l15 = lane & 15, lq = lane >> 4;
  const int wid = tid >> 6;
  const int wr = wid >> 1, wc = wid & 1;   // wave tile 32(M) x 64(N)
  const int bm = blockIdx.y, bn = blockIdx.x;
  f32x4 acc[2][4] = {};
  const int srow = tid >> 3;
  const int schk = (tid & 7) ^ (srow & 7);
  const bf16* aB = A + (size_t)(bm * 64 + srow) * K + schk * 8;
  const bf16* bB = Bw + (size_t)(bn * 128 + srow) * K + schk * 8;

  int aoff[2][2], boff[2][4];
#pragma unroll
  for (int ks = 0; ks < 2; ++ks) {
#pragma unroll
    for (int f = 0; f < 2; ++f) {
      int arow = wr * 32 + f * 16 + l15;
      aoff[ks][f] = arow * 64 + (((ks * 4 + lq) ^ (arow & 7)) * 8);
    }
#pragma unroll
    for (int f = 0; f < 4; ++f) {
      int brow = wc * 64 + f * 16 + l15;
      boff[ks][f] = brow * 64 + (((ks * 4 + lq) ^ (brow & 7)) * 8);
    }
  }

  for (int kt = 0; kt < K; kt += 64) {
#pragma unroll
    for (int r = 0; r < 2; ++r)
      gld_lds16(aB + (size_t)(r * 32) * K + kt, As + r * 2048 + tid * 8);
#pragma unroll
    for (int r = 0; r < 4; ++r)
      gld_lds16(bB + (size_t)(r * 32) * K + kt, Bs + r * 2048 + tid * 8);
    __syncthreads();
#pragma unroll
    for (int ks = 0; ks < 2; ++ks) {
      bf16x8 af[2], bfr[4];
#pragma unroll
      for (int mf = 0; mf < 2; ++mf)
        af[mf] = *(const bf16x8*)&As[aoff[ks][mf]];
#pragma unroll
      for (int nf = 0; nf < 4; ++nf)
        bfr[nf] = *(const bf16x8*)&Bs[boff[ks][nf]];
#pragma unroll
      for (int mf = 0; mf < 2; ++mf)
#pragma unroll
        for (int nf = 0; nf < 4; ++nf)
          acc[mf][nf] = __builtin_amdgcn_mfma_f32_16x16x32_bf16(af[mf], bfr[nf], acc[mf][nf], 0, 0, 0);
    }
    __syncthreads();
  }
#pragma unroll
  for (int mf = 0; mf < 2; ++mf)
#pragma unroll
    for (int nf = 0; nf < 4; ++nf)
#pragma unroll
      for (int r = 0; r < 4; ++r) {
        int row = bm * 64 + wr * 32 + mf * 16 + lq * 4 + r;
        int col = bn * 128 + wc * 64 + nf * 16 + l15;
        C[(size_t)row * N + col] = acc[mf][nf][r];
      }
}

// ---------------- flash attention (ROUND-10 EXACT CONFIG — measured best) ----------
__global__ __launch_bounds__(256, 2)
void attn_kernel(const bf16* __restrict__ qr, const bf16* __restrict__ kr,
                 const bf16* __restrict__ vt, const bf16* __restrict__ maskb,
                 float* __restrict__ ctx) {
  __shared__ bf16 Kt[2][64 * 64];
  __shared__ bf16 Vt[2][64 * 64];
  __shared__ bf16 Pl[4][16 * 64];
  const int tid = threadIdx.x, lane = tid & 63, wid = tid >> 6;
  const int l15 = lane & 15, lq = lane >> 4;
  const int qt = blockIdx.x, bh = blockIdx.y;
  const int b = bh >> 4, hh = bh & 15;
  const size_t baseQ = ((size_t)bh * SEQ + qt * 64 + wid * 16) * 64;
  bf16x8 aq[2];
  aq[0] = *(const bf16x8*)&qr[baseQ + (size_t)l15 * 64 + 0 + lq * 8];
  aq[1] = *(const bf16x8*)&qr[baseQ + (size_t)l15 * 64 + 32 + lq * 8];
  float mrow[4], lrow[4];
  f32x4 oacc[4] = {};
#pragma unroll
  for (int r = 0; r < 4; ++r) { mrow[r] = -1e30f; lrow[r] = 0.0f; }
  const int srow = tid >> 3;
  const int schk = (tid & 7) ^ (srow & 7);
  const bf16* kBase = kr + ((size_t)bh * SEQ + srow) * 64 + schk * 8;
  const bf16* vBase = vt + ((size_t)bh * 64 + srow) * SEQ + schk * 8;

#define ASTAGE(bi_, kv_)                                                        \
  do {                                                                          \
    gld_lds16(kBase + (size_t)(kv_) * 64, &Kt[bi_][0] + tid * 8);               \
    gld_lds16(kBase + (size_t)((kv_) + 32) * 64, &Kt[bi_][0] + 2048 + tid * 8); \
    gld_lds16(vBase + (kv_), &Vt[bi_][0] + tid * 8);                            \
    gld_lds16(vBase + (size_t)32 * SEQ + (kv_), &Vt[bi_][0] + 2048 + tid * 8);  \
  } while (0)

  ASTAGE(0, 0);
  WAITVM0();
  BARRIER();
  for (int kv0 = 0; kv0 < SEQ; kv0 += 64) {
    const int cur = (kv0 >> 6) & 1;
    if (kv0 + 64 < SEQ) { ASTAGE(cur ^ 1, kv0 + 64); MEMFENCE(); }
    const bf16* kt = &Kt[cur][0];
    const bf16* vtl = &Vt[cur][0];
    f32x4 sacc[4] = {};
    __builtin_amdgcn_s_setprio(1);
#pragma unroll
    for (int k0 = 0; k0 < 2; ++k0) {
#pragma unroll
      for (int nf = 0; nf < 4; ++nf) {
        bf16x8 bk = *(const bf16x8*)&kt[(nf * 16 + l15) * 64 + (((k0 * 4 + lq) ^ (l15 & 7)) << 3)];
        sacc[nf] = __builtin_amdgcn_mfma_f32_16x16x32_bf16(aq[k0], bk, sacc[nf], 0, 0, 0);
      }
    }
    __builtin_amdgcn_s_setprio(0);
    const int qg0 = qt * 64 + wid * 16 + lq * 4;
#pragma unroll
    for (int nf = 0; nf < 4; ++nf) {
      int kvg = kv0 + nf * 16 + l15;
#pragma unroll
      for (int r = 0; r < 4; ++r)
        sacc[nf][r] += (float)maskb[(size_t)(qg0 + r) * SEQ + kvg];
    }
    float fac[4];
#pragma unroll
    for (int r = 0; r < 4; ++r) {
      float v = fmaxf(fmaxf(sacc[0][r], sacc[1][r]), fmaxf(sacc[2][r], sacc[3][r]));
      v = fmaxf(v, __shfl_xor(v, 1));
      v = fmaxf(v, __shfl_xor(v, 2));
      v = fmaxf(v, __shfl_xor(v, 4));
      v = fmaxf(v, __shfl_xor(v, 8));
      float mnew = fmaxf(mrow[r], v);
      fac[r] = __expf(mrow[r] - mnew);
      mrow[r] = mnew;
    }
    float rs[4] = {0, 0, 0, 0};
#pragma unroll
    for (int nf = 0; nf < 4; ++nf)
#pragma unroll
      for (int r = 0; r < 4; ++r) {
        float pv = __expf(sacc[nf][r] - mrow[r]);
        sacc[nf][r] = pv;
        rs[r] += pv;
      }
#pragma unroll
    for (int r = 0; r < 4; ++r) {
      float v = rs[r];
      v += __shfl_xor(v, 1); v += __shfl_xor(v, 2);
      v += __shfl_xor(v, 4); v += __shfl_xor(v, 8);
      lrow[r] = lrow[r] * fac[r] + v;
    }
#pragma unroll
    for (int nf = 0; nf < 4; ++nf)
#pragma unroll
      for (int r = 0; r < 4; ++r) {
        int qrow = lq * 4 + r;
        int col = nf * 16 + l15;
        Pl[wid][qrow * 64 + ((((col >> 3) ^ (qrow & 7))) << 3) + (col & 7)] = (bf16)sacc[nf][r];
      }
#pragma unroll
    for (int nf = 0; nf < 4; ++nf)
#pragma unroll
      for (int r = 0; r < 4; ++r)
        oacc[nf][r] *= fac[r];
    __builtin_amdgcn_s_setprio(1);
#pragma unroll
    for (int k0 = 0; k0 < 2; ++k0) {
      bf16x8 ap = *(const bf16x8*)&Pl[wid][l15 * 64 + (((k0 * 4 + lq) ^ (l15 & 7)) << 3)];
#pragma unroll
      for (int nf = 0; nf < 4; ++nf) {
        bf16x8 bv = *(const bf16x8*)&vtl[(nf * 16 + l15) * 64 + (((k0 * 4 + lq) ^ (l15 & 7)) << 3)];
        oacc[nf] = __builtin_amdgcn_mfma_f32_16x16x32_bf16(ap, bv, oacc[nf], 0, 0, 0);
      }
    }
    __builtin_amdgcn_s_setprio(0);
    WAITVM0();
    BARRIER();
  }
#undef ASTAGE
#pragma unroll
  for (int nf = 0; nf < 4; ++nf)
#pragma unroll
    for (int r = 0; r < 4; ++r) {
      int row = qt * 64 + wid * 16 + lq * 4 + r;
      int col = hh * 64 + nf * 16 + l15;
      ctx[((size_t)b * SEQ + row) * HID + col] = oacc[nf][r] / lrow[r];
    }
}

// ---------------- launch ----------------
extern "C" void kernel_launch(void* const* d_in, const int* in_sizes, int n_in,
                              void* d_out, int out_size, void* d_ws, size_t ws_size,
                              hipStream_t stream) {
  const float* qin    = (const float*)d_in[0];
  const float* kin    = (const float*)d_in[1];
  const float* vin    = (const float*)d_in[2];
  const float* mask   = (const float*)d_in[3];
  const float* qkv_bw = (const float*)d_in[4];
  const float* qkv_sw = (const float*)d_in[5];
  const float* qkv_sc = (const float*)d_in[6];
  const float* out_bw = (const float*)d_in[7];
  const float* out_sw = (const float*)d_in[8];
  const float* out_sc = (const float*)d_in[9];
  char* ws = (char*)d_ws;
  bf16* Wq   = (bf16*)(ws + WQ_OFF);
  bf16* Aq   = (bf16*)(ws + AQ_OFF);
  bf16* vrow = (bf16*)(ws + VR_OFF);
  float2* tcs = (float2*)(ws + TC_OFF);
  bf16* qr   = (bf16*)(ws + QR_OFF);
  bf16* kr   = (bf16*)(ws + KR_OFF);
  bf16* vt   = (bf16*)(ws + VB_OFF);
  float* ctx = (float*)(ws + CTX_OFF);
  bf16* A2   = (bf16*)(ws + A2_OFF);
  bf16* W2   = (bf16*)(ws + W2_OFF);
  bf16* mb   = (bf16*)(ws + MB_OFF);

  tprep_kernel<<<256, 256, 0, stream>>>(tcs);
  wprep_kernel<<<dim3(H3 / 256, H3), 256, 0, stream>>>(qkv_bw, qkv_sw, qkv_sc, Wq, H3);
  act_qkv_kernel<<<dim3(H3 / 256, MROWS), 256, 0, stream>>>(qin, kin, vin, Aq);
  gemm1_kernel<<<dim3(H3 / 128, MROWS / 128), 256, 0, stream>>>(Aq, Wq, qr, kr, vrow, tcs, K1DIM);
  maskprep_kernel<<<(SEQ * SEQ) / 1024, 256, 0, stream>>>(mask, mb);   // Wq dead now
  vtrans_kernel<<<dim3(SEQ / 64, BATCH * NHEAD), 256, 0, stream>>>(vrow, vt);
  attn_kernel<<<dim3(SEQ / 64, BATCH * NHEAD), 256, 0, stream>>>(qr, kr, vt, mb, ctx);
  act_out_kernel<<<dim3(HID / 256, MROWS), 256, 0, stream>>>(ctx, A2);
  wprep_kernel<<<dim3(HID / 256, HID), 256, 0, stream>>>(out_bw, out_sw, out_sc, W2, HID);
  gemm2_kernel<<<dim3(HID / 128, MROWS / 64), 256, 0, stream>>>(A2, W2, (float*)d_out, HID, K2DIM);
}